// Round 2
// baseline (1382.085 us; speedup 1.0000x reference)
//
#include <hip/hip_runtime.h>
#include <hip/hip_bf16.h>
#include <stdint.h>

typedef float f32x4 __attribute__((ext_vector_type(4)));
typedef short bf16x8 __attribute__((ext_vector_type(8)));

#define DIM 384

__device__ __forceinline__ ushort to_bf16(float f) {
    union { float f; uint32_t u; } v; v.f = f;
    uint32_t u = v.u;
    return (ushort)((u + 0x7fffu + ((u >> 16) & 1u)) >> 16);   // RNE
}
__device__ __forceinline__ float sigmoid_(float x) { return 1.0f / (1.0f + __expf(-x)); }
__device__ __forceinline__ float tanh_(float x)    { return 1.0f - 2.0f / (__expf(2.0f * x) + 1.0f); }

// Swizzled concat weight W'[g][k] = (k<384 ? w_ih : w_hh), bf16; fragment layout:
// dst[((tile*24 + kc)*64 + quad*16 + (g&15))*8 + j]  for k = kc*32 + quad*8 + j
__global__ void prep_w(const float* __restrict__ w_ih, const float* __restrict__ w_hh,
                       ushort* __restrict__ wswz) {
    int tid = blockIdx.x * blockDim.x + threadIdx.x;   // 1152 * 96
    if (tid >= 1152 * 96) return;
    int g  = tid / 96;
    int k  = (tid % 96) * 8;
    int kc = k >> 5;
    int q  = (k >> 3) & 3;
    int tile = g >> 4;
    int lane = q * 16 + (g & 15);
    ushort* dst = wswz + ((size_t)(tile * 24 + kc) * 64 + lane) * 8;
    const float* src = (k < 384) ? (w_ih + (size_t)g * 384 + k)
                                 : (w_hh + (size_t)g * 384 + (k - 384));
#pragma unroll
    for (int j = 0; j < 8; ++j) dst[j] = to_bf16(src[j]);
}

__global__ void embed_gather(const int* __restrict__ tok, const float* __restrict__ table,
                             ushort* __restrict__ xleaf, int n_leaves) {
    int tid = blockIdx.x * blockDim.x + threadIdx.x;   // n_leaves * 48
    if (tid >= n_leaves * 48) return;
    int leaf = tid / 48, i = tid % 48;
    const float* src = table + (size_t)tok[leaf] * 384 + i * 8;
    ushort* dst = xleaf + (size_t)leaf * 384 + i * 8;
#pragma unroll
    for (int j = 0; j < 8; ++j) dst[j] = to_bf16(src[j]);
}

// Level 5 fused kernel: 512 threads = 8 waves, 16 parents/block, grid 256.
// Wave w owns rz-tiles w*6..w*6+5 (gates w*96..) and n-tiles 48+w*3.. (dims w*48..).
__global__ __launch_bounds__(512, 2)
void level5_kernel(const ushort* __restrict__ Xc, const ushort* __restrict__ W,
                   const float* __restrict__ b_ih, const float* __restrict__ b_hh,
                   ushort* __restrict__ Xo, float* __restrict__ Ho) {
    __shared__ alignas(16) ushort A[16][776];   // [parent][k]: k<384 = x_t, k>=384 = h (+8 pad)
    __shared__ float RZ[16][769];               // sigmoid(r) at [m][d], sigmoid(z) at [m][384+d]

    const int tid  = threadIdx.x;
    const int wave = tid >> 6, lane = tid & 63;
    const int quad = lane >> 4, col = lane & 15;
    const int blk  = blockIdx.x;

    float bsum[6], bin[3], bhn[3];
#pragma unroll
    for (int j = 0; j < 6; ++j) { int g = wave * 96 + j * 16 + col; bsum[j] = b_ih[g] + b_hh[g]; }
#pragma unroll
    for (int j = 0; j < 3; ++j) { int d = wave * 48 + j * 16 + col; bin[j] = b_ih[768 + d]; bhn[j] = b_hh[768 + d]; }

    float hreg[3][4], xsum[3][4];
#pragma unroll
    for (int j = 0; j < 3; ++j) {
        int d = wave * 48 + j * 16 + col;
#pragma unroll
        for (int r = 0; r < 4; ++r) {
            hreg[j][r] = 0.0f; xsum[j][r] = 0.0f;
            A[quad * 4 + r][384 + d] = 0;       // leaf h = 0
        }
    }
    // x fill for t=0 (child 7)
    {
        int m = tid >> 5, i = tid & 31;
        int gp = blk * 16 + m;
        const uint4* s = (const uint4*)(Xc + ((size_t)gp * 8 + 7) * 384);
        uint4* dst = (uint4*)&A[m][0];
        for (int sl = i; sl < 48; sl += 32) dst[sl] = s[sl];
    }
    __syncthreads();

    for (int t = 0; t < 8; ++t) {
        f32x4 accrz[6], accin[3], acchn[3];
#pragma unroll
        for (int j = 0; j < 6; ++j) accrz[j] = (f32x4){0.f, 0.f, 0.f, 0.f};
#pragma unroll
        for (int j = 0; j < 3; ++j) { accin[j] = (f32x4){0.f, 0.f, 0.f, 0.f}; acchn[j] = (f32x4){0.f, 0.f, 0.f, 0.f}; }

        for (int kc = 0; kc < 24; ++kc) {
            bf16x8 aF = *(const bf16x8*)&A[col][kc * 32 + quad * 8];
#pragma unroll
            for (int j = 0; j < 6; ++j) {
                int tile = wave * 6 + j;
                bf16x8 bF = *(const bf16x8*)(W + ((size_t)(tile * 24 + kc) * 64 + lane) * 8);
                accrz[j] = __builtin_amdgcn_mfma_f32_16x16x32_bf16(aF, bF, accrz[j], 0, 0, 0);
            }
#pragma unroll
            for (int j = 0; j < 3; ++j) {
                int tile = 48 + wave * 3 + j;
                bf16x8 bF = *(const bf16x8*)(W + ((size_t)(tile * 24 + kc) * 64 + lane) * 8);
                if (kc < 12) accin[j] = __builtin_amdgcn_mfma_f32_16x16x32_bf16(aF, bF, accin[j], 0, 0, 0);
                else         acchn[j] = __builtin_amdgcn_mfma_f32_16x16x32_bf16(aF, bF, acchn[j], 0, 0, 0);
            }
        }

#pragma unroll
        for (int j = 0; j < 6; ++j) {
            int g = wave * 96 + j * 16 + col;
#pragma unroll
            for (int r = 0; r < 4; ++r)
                RZ[quad * 4 + r][g] = sigmoid_(accrz[j][r] + bsum[j]);
        }
        __syncthreads();

#pragma unroll
        for (int j = 0; j < 3; ++j) {
            int d = wave * 48 + j * 16 + col;
#pragma unroll
            for (int r = 0; r < 4; ++r) {
                int row = quad * 4 + r;
                float rv = RZ[row][d], zv = RZ[row][384 + d];
                float nv = tanh_(accin[j][r] + bin[j] + rv * (acchn[j][r] + bhn[j]));
                float hnew = (1.0f - zv) * nv + zv * hreg[j][r];
                hreg[j][r] = hnew; xsum[j][r] += hnew;
                A[row][384 + d] = to_bf16(hnew);
            }
        }
        if (t < 7) {
            int m = tid >> 5, i = tid & 31;
            int gp = blk * 16 + m;
            const uint4* s = (const uint4*)(Xc + ((size_t)gp * 8 + (6 - t)) * 384);
            uint4* dst = (uint4*)&A[m][0];
            for (int sl = i; sl < 48; sl += 32) dst[sl] = s[sl];
        }
        __syncthreads();
    }

#pragma unroll
    for (int j = 0; j < 3; ++j) {
        int d = wave * 48 + j * 16 + col;
#pragma unroll
        for (int r = 0; r < 4; ++r) {
            int gp = blk * 16 + quad * 4 + r;
            float xo = xsum[j][r] * 0.125f;
            Xo[(size_t)gp * 384 + d] = to_bf16(xo);
            Ho[(size_t)gp * 384 + d] = hreg[j][r];
        }
    }
}

// Tail: per-level init (h0 = mean child h, zero xsum)
__global__ void init_level(const float* __restrict__ Hc, float* __restrict__ Hf,
                           ushort* __restrict__ Hb, float* __restrict__ xsum, int P) {
    int tid = blockIdx.x * blockDim.x + threadIdx.x;
    if (tid >= P * 384) return;
    int p = tid / 384, d = tid % 384;
    float h0 = 0.0f;
#pragma unroll
    for (int c = 0; c < 8; ++c) h0 += Hc[((size_t)p * 8 + c) * 384 + d];
    h0 *= 0.125f;
    Hf[tid] = h0; Hb[tid] = to_bf16(h0); xsum[tid] = 0.0f;
}

// One GRU step. Block = 256 thr (4 waves). blockIdx.x = d-slice (24), blockIdx.y = m-group.
// Wave w handles rows m0 = blockIdx.y*64 + w*16. Block owns gate triple (r,z,n) for dims
// d0..d0+15, so the full h-update is local.
__global__ __launch_bounds__(256, 4)
void step_kernel(const ushort* __restrict__ Xc, const ushort* __restrict__ Hb_in,
                 ushort* __restrict__ Hb_out, float* __restrict__ Hf,
                 float* __restrict__ xsum, const ushort* __restrict__ W,
                 const float* __restrict__ b_ih, const float* __restrict__ b_hh,
                 ushort* __restrict__ Xo, float* __restrict__ fout,
                 int P, int child, int last) {
    const int tid  = threadIdx.x;
    const int wave = tid >> 6, lane = tid & 63;
    const int quad = lane >> 4, col = lane & 15;
    const int ds = blockIdx.x, d0 = ds * 16;
    const int m0 = blockIdx.y * 64 + wave * 16;

    const int par = m0 + col;           // row this lane feeds into the A fragment
    const bool av = par < P;
    const ushort* xrow = Xc + ((size_t)par * 8 + child) * 384;
    const ushort* hrow = Hb_in + (size_t)par * 384;
    const ushort* Wr = W + (size_t)(ds)      * 24 * 64 * 8;
    const ushort* Wz = W + (size_t)(24 + ds) * 24 * 64 * 8;
    const ushort* Wn = W + (size_t)(48 + ds) * 24 * 64 * 8;

    f32x4 accr = (f32x4){0.f,0.f,0.f,0.f}, accz = accr, accin = accr, acchn = accr;
    const bf16x8 zf = (bf16x8){0,0,0,0,0,0,0,0};

    for (int kc = 0; kc < 24; ++kc) {
        bf16x8 aF = zf;
        if (av) {
            const ushort* src = (kc < 12) ? (xrow + kc * 32 + quad * 8)
                                          : (hrow + (kc - 12) * 32 + quad * 8);
            aF = *(const bf16x8*)src;
        }
        size_t wo = ((size_t)kc * 64 + lane) * 8;
        accr = __builtin_amdgcn_mfma_f32_16x16x32_bf16(aF, *(const bf16x8*)(Wr + wo), accr, 0, 0, 0);
        accz = __builtin_amdgcn_mfma_f32_16x16x32_bf16(aF, *(const bf16x8*)(Wz + wo), accz, 0, 0, 0);
        bf16x8 bn = *(const bf16x8*)(Wn + wo);
        if (kc < 12) accin = __builtin_amdgcn_mfma_f32_16x16x32_bf16(aF, bn, accin, 0, 0, 0);
        else         acchn = __builtin_amdgcn_mfma_f32_16x16x32_bf16(aF, bn, acchn, 0, 0, 0);
    }

    const int d = d0 + col;
    const float br = b_ih[d] + b_hh[d];
    const float bz = b_ih[384 + d] + b_hh[384 + d];
    const float bi = b_ih[768 + d], bh = b_hh[768 + d];
#pragma unroll
    for (int r = 0; r < 4; ++r) {
        int m = m0 + quad * 4 + r;
        if (m < P) {
            float rv = sigmoid_(accr[r] + br);
            float zv = sigmoid_(accz[r] + bz);
            float nv = tanh_(accin[r] + bi + rv * (acchn[r] + bh));
            size_t idx = (size_t)m * 384 + d;
            float hp = Hf[idx];
            float hn = (1.0f - zv) * nv + zv * hp;
            Hf[idx] = hn;
            Hb_out[idx] = to_bf16(hn);
            float xs = xsum[idx] + hn;
            if (!last) {
                xsum[idx] = xs;
            } else {
                float xo = xs * 0.125f;
                Xo[idx] = to_bf16(xo);
                if (fout != nullptr) fout[d] = xo;
            }
        }
    }
}

extern "C" void kernel_launch(void* const* d_in, const int* in_sizes, int n_in,
                              void* d_out, int out_size, void* d_ws, size_t ws_size,
                              hipStream_t stream) {
    const int*   tok   = (const int*)d_in[0];
    const float* table = (const float*)d_in[1];
    const float* w_ih  = (const float*)d_in[2];
    const float* w_hh  = (const float*)d_in[3];
    const float* b_ih  = (const float*)d_in[4];
    const float* b_hh  = (const float*)d_in[5];
    float* out = (float*)d_out;

    char* ws = (char*)d_ws;
    size_t off = 0;
    auto alloc = [&](size_t bytes) -> void* {
        void* p = ws + off;
        off = (off + bytes + 255) & ~(size_t)255;
        return p;
    };
    ushort* wswz = (ushort*)alloc((size_t)1152 * 768 * 2);
    ushort* XA   = (ushort*)alloc((size_t)32768 * 384 * 2);   // leaf x
    ushort* XB   = (ushort*)alloc((size_t)4096 * 384 * 2);    // level-5 out x
    float*  HA   = (float*)alloc((size_t)4096 * 384 * 4);     // level-5 out h

    // per tail level: Hf (f32), Hb ping/pong (bf16), xsum (f32), Xo (bf16)
    auto tailbuf = [&](int P, float*& Hf, ushort*& Ha, ushort*& Hb2, float*& xs, ushort*& Xo) {
        Hf  = (float*) alloc((size_t)P * 384 * 4);
        Ha  = (ushort*)alloc((size_t)P * 384 * 2);
        Hb2 = (ushort*)alloc((size_t)P * 384 * 2);
        xs  = (float*) alloc((size_t)P * 384 * 4);
        Xo  = (ushort*)alloc((size_t)P * 384 * 2);
    };
    float *Hf4, *xs4, *Hf3, *xs3, *Hf2, *xs2, *Hf1, *xs1;
    ushort *H4a, *H4b, *Xo4, *H3a, *H3b, *Xo3, *H2a, *H2b, *Xo2, *H1a, *H1b, *Xo1;
    tailbuf(512, Hf4, H4a, H4b, xs4, Xo4);
    tailbuf(64,  Hf3, H3a, H3b, xs3, Xo3);
    tailbuf(8,   Hf2, H2a, H2b, xs2, Xo2);
    tailbuf(1,   Hf1, H1a, H1b, xs1, Xo1);

    prep_w<<<(1152 * 96 + 255) / 256, 256, 0, stream>>>(w_ih, w_hh, wswz);
    embed_gather<<<(32768 * 48 + 255) / 256, 256, 0, stream>>>(tok, table, XA, 32768);

    // level 5: fused, 4096 parents, leaf children (h=0)
    level5_kernel<<<256, 512, 0, stream>>>(XA, wswz, b_ih, b_hh, XB, HA);

    // tail levels: init + 8 per-step kernels each
    auto run_level = [&](const ushort* Xc, const float* Hc_child, float* Hf,
                         ushort* Ha, ushort* Hb, float* xs, ushort* Xo,
                         float* fout, int P) {
        init_level<<<(P * 384 + 255) / 256, 256, 0, stream>>>(Hc_child, Hf, Ha, xs, P);
        dim3 grid(24, (P + 63) / 64);
        for (int t = 0; t < 8; ++t) {
            const ushort* hin = (t & 1) ? Hb : Ha;
            ushort*       hout = (t & 1) ? Ha : Hb;
            step_kernel<<<grid, 256, 0, stream>>>(Xc, hin, hout, Hf, xs, wswz, b_ih, b_hh,
                                                  Xo, (t == 7) ? fout : nullptr,
                                                  P, 7 - t, (t == 7) ? 1 : 0);
        }
    };

    run_level(XB,  HA,  Hf4, H4a, H4b, xs4, Xo4, nullptr, 512);
    run_level(Xo4, Hf4, Hf3, H3a, H3b, xs3, Xo3, nullptr, 64);
    run_level(Xo3, Hf3, Hf2, H2a, H2b, xs2, Xo2, nullptr, 8);
    run_level(Xo2, Hf2, Hf1, H1a, H1b, xs1, Xo1, out, 1);
}

// Round 3
// 1329.511 us; speedup vs baseline: 1.0395x; 1.0395x over previous
//
#include <hip/hip_runtime.h>
#include <hip/hip_bf16.h>
#include <stdint.h>

typedef float f32x4 __attribute__((ext_vector_type(4)));
typedef short bf16x8 __attribute__((ext_vector_type(8)));

__device__ __forceinline__ ushort to_bf16(float f) {
    union { float f; uint32_t u; } v; v.f = f;
    uint32_t u = v.u;
    return (ushort)((u + 0x7fffu + ((u >> 16) & 1u)) >> 16);   // RNE
}
__device__ __forceinline__ float sigmoid_(float x) { return 1.0f / (1.0f + __expf(-x)); }
__device__ __forceinline__ float tanh_(float x)    { return 1.0f - 2.0f / (__expf(2.0f * x) + 1.0f); }

// Swizzled concat weight W'[g][k] = (k<384 ? w_ih : w_hh), bf16; fragment layout:
// elem ((tile*24 + kc)*64 + quad*16 + (g&15))*8 + j  for k = kc*32 + quad*8 + j
__global__ void prep_w(const float* __restrict__ w_ih, const float* __restrict__ w_hh,
                       ushort* __restrict__ wswz) {
    int tid = blockIdx.x * blockDim.x + threadIdx.x;   // 1152 * 96
    if (tid >= 1152 * 96) return;
    int g  = tid / 96;
    int k  = (tid % 96) * 8;
    int kc = k >> 5;
    int q  = (k >> 3) & 3;
    int tile = g >> 4;
    int lane = q * 16 + (g & 15);
    ushort* dst = wswz + ((size_t)(tile * 24 + kc) * 64 + lane) * 8;
    const float* src = (k < 384) ? (w_ih + (size_t)g * 384 + k)
                                 : (w_hh + (size_t)g * 384 + (k - 384));
#pragma unroll
    for (int j = 0; j < 8; ++j) dst[j] = to_bf16(src[j]);
}

__global__ void embed_gather(const int* __restrict__ tok, const float* __restrict__ table,
                             ushort* __restrict__ xleaf, int n_leaves) {
    int tid = blockIdx.x * blockDim.x + threadIdx.x;   // n_leaves * 48
    if (tid >= n_leaves * 48) return;
    int leaf = tid / 48, i = tid % 48;
    const float* src = table + (size_t)tok[leaf] * 384 + i * 8;
    bf16x8 v;
#pragma unroll
    for (int j = 0; j < 8; ++j) v[j] = (short)to_bf16(src[j]);
    *(bf16x8*)(xleaf + (size_t)leaf * 384 + i * 8) = v;
}

// Tail-level init: h0 = mean of 8 children's f32 hidden states.
__global__ void init_h(const float* __restrict__ Hc, float* __restrict__ Hf,
                       ushort* __restrict__ Hb, int P) {
    int tid = blockIdx.x * blockDim.x + threadIdx.x;
    if (tid >= P * 384) return;
    int p = tid / 384, d = tid % 384;
    float h0 = 0.0f;
#pragma unroll
    for (int c = 0; c < 8; ++c) h0 += Hc[((size_t)p * 8 + c) * 384 + d];
    h0 *= 0.125f;
    Hf[tid] = h0; Hb[tid] = to_bf16(h0);
}

// One GRU step for one level. No LDS, no barriers: the (r,z,n) gate triple for a
// given (row m, dim d) all land in the SAME lane/reg, so the full GRU update is
// lane-local. Block = 512 thr = 8 waves; wave w owns rows m0 = by*128 + w*16.
// blockIdx.x = ds in [0,8): dims ds*48..ds*48+47 (3 16-col tiles per gate).
// flags: 1 = first step (xsum write-only), 2 = h is zero (level-5 t0), 4 = last step.
__global__ __launch_bounds__(512)
void gru_step(const ushort* __restrict__ Xc, const ushort* __restrict__ Hb_in,
              ushort* __restrict__ Hb_out, float* __restrict__ Hf,
              float* __restrict__ xsum, const ushort* __restrict__ W,
              const float* __restrict__ b_ih, const float* __restrict__ b_hh,
              ushort* __restrict__ Xo, float* __restrict__ fout,
              int P, int child, int flags) {
    const int wave = threadIdx.x >> 6, lane = threadIdx.x & 63;
    const int quad = lane >> 4, col = lane & 15;
    const int m0 = blockIdx.y * 128 + wave * 16;
    if (m0 >= P) return;                       // no barriers -> safe early exit
    const int ds = blockIdx.x;
    const bool first = flags & 1, hzero = (flags & 2) != 0, last = flags & 4;

    const int par = m0 + col;
    const bool av = par < P;
    const ushort* xrow = Xc + ((size_t)par * 8 + child) * 384 + quad * 8;
    const ushort* hrow = Hb_in + (size_t)par * 384 + quad * 8;
    const ushort* Wl = W + (size_t)lane * 8;   // tile t, chunk kc at Wl + t*12288 + kc*512
    const int tr = ds * 3, tz = 24 + ds * 3, tn = 48 + ds * 3;

    f32x4 accr[3], accz[3], accn1[3], accn2[3];
#pragma unroll
    for (int j = 0; j < 3; ++j) {
        accr[j] = (f32x4){0.f, 0.f, 0.f, 0.f}; accz[j] = accr[j];
        accn1[j] = accr[j]; accn2[j] = accr[j];
    }

    const int kcmax = hzero ? 12 : 24;         // h==0: skip the h half entirely
    for (int kc = 0; kc < kcmax; ++kc) {
        bf16x8 aF = (bf16x8){0, 0, 0, 0, 0, 0, 0, 0};
        if (av) {
            if (kc < 12) aF = *(const bf16x8*)(xrow + kc * 32);
            else         aF = *(const bf16x8*)(hrow + (kc - 12) * 32);
        }
        size_t kb = (size_t)kc * 512;
#pragma unroll
        for (int j = 0; j < 3; ++j) {
            bf16x8 bR = *(const bf16x8*)(Wl + (size_t)(tr + j) * 12288 + kb);
            accr[j] = __builtin_amdgcn_mfma_f32_16x16x32_bf16(aF, bR, accr[j], 0, 0, 0);
            bf16x8 bZ = *(const bf16x8*)(Wl + (size_t)(tz + j) * 12288 + kb);
            accz[j] = __builtin_amdgcn_mfma_f32_16x16x32_bf16(aF, bZ, accz[j], 0, 0, 0);
            bf16x8 bN = *(const bf16x8*)(Wl + (size_t)(tn + j) * 12288 + kb);
            if (kc < 12) accn1[j] = __builtin_amdgcn_mfma_f32_16x16x32_bf16(aF, bN, accn1[j], 0, 0, 0);
            else         accn2[j] = __builtin_amdgcn_mfma_f32_16x16x32_bf16(aF, bN, accn2[j], 0, 0, 0);
        }
    }

#pragma unroll
    for (int j = 0; j < 3; ++j) {
        const int d = ds * 48 + j * 16 + col;
        const float br = b_ih[d] + b_hh[d];
        const float bz = b_ih[384 + d] + b_hh[384 + d];
        const float bi = b_ih[768 + d], bh = b_hh[768 + d];
#pragma unroll
        for (int r = 0; r < 4; ++r) {
            const int m = m0 + quad * 4 + r;
            if (m < P) {
                const size_t idx = (size_t)m * 384 + d;
                float rv = sigmoid_(accr[j][r] + br);
                float zv = sigmoid_(accz[j][r] + bz);
                float nv = tanh_(accn1[j][r] + bi + rv * (accn2[j][r] + bh));
                float hp = hzero ? 0.0f : Hf[idx];
                float hn = (1.0f - zv) * nv + zv * hp;
                Hf[idx] = hn;
                Hb_out[idx] = to_bf16(hn);
                float xs = first ? hn : xsum[idx] + hn;
                if (!last) {
                    xsum[idx] = xs;
                } else {
                    float xo = xs * 0.125f;
                    Xo[idx] = to_bf16(xo);
                    if (fout != nullptr && m == 0) fout[d] = xo;
                }
            }
        }
    }
}

extern "C" void kernel_launch(void* const* d_in, const int* in_sizes, int n_in,
                              void* d_out, int out_size, void* d_ws, size_t ws_size,
                              hipStream_t stream) {
    const int*   tok   = (const int*)d_in[0];
    const float* table = (const float*)d_in[1];
    const float* w_ih  = (const float*)d_in[2];
    const float* w_hh  = (const float*)d_in[3];
    const float* b_ih  = (const float*)d_in[4];
    const float* b_hh  = (const float*)d_in[5];
    float* out = (float*)d_out;

    char* ws = (char*)d_ws;
    size_t off = 0;
    auto alloc = [&](size_t bytes) -> void* {
        void* p = ws + off;
        off = (off + bytes + 255) & ~(size_t)255;
        return p;
    };
    ushort* wswz = (ushort*)alloc((size_t)1152 * 768 * 2);
    ushort* XA   = (ushort*)alloc((size_t)32768 * 384 * 2);   // leaf x (bf16)

    struct Lvl { ushort *Ha, *Hb, *Xo; float *Hf, *xs; };
    auto mk = [&](int P) -> Lvl {
        Lvl l;
        l.Ha = (ushort*)alloc((size_t)P * 384 * 2);
        l.Hb = (ushort*)alloc((size_t)P * 384 * 2);
        l.Xo = (ushort*)alloc((size_t)P * 384 * 2);
        l.Hf = (float*) alloc((size_t)P * 384 * 4);
        l.xs = (float*) alloc((size_t)P * 384 * 4);
        return l;
    };
    Lvl L5 = mk(4096), L4 = mk(512), L3 = mk(64), L2 = mk(8), L1 = mk(1);

    prep_w<<<(1152 * 96 + 255) / 256, 256, 0, stream>>>(w_ih, w_hh, wswz);
    embed_gather<<<(32768 * 48 + 255) / 256, 256, 0, stream>>>(tok, table, XA, 32768);

    auto run_level = [&](const ushort* Xc, const float* Hc_child, Lvl& L,
                         float* fout, int P, bool leaf) {
        if (!leaf)
            init_h<<<(P * 384 + 255) / 256, 256, 0, stream>>>(Hc_child, L.Hf, L.Ha, P);
        dim3 grid(8, (P + 127) / 128);
        for (int t = 0; t < 8; ++t) {
            const ushort* hin = (t & 1) ? L.Ha : L.Hb;   // t0 out=Ha (in unused if leaf)
            ushort*       hout = (t & 1) ? L.Hb : L.Ha;
            if (!leaf && t == 0) { hin = L.Ha; hout = L.Hb; }  // t0: read init'd Ha -> Hb
            int flags = (t == 0 ? 1 : 0) | (leaf && t == 0 ? 2 : 0) | (t == 7 ? 4 : 0);
            gru_step<<<grid, 512, 0, stream>>>(Xc, hin, hout, L.Hf, L.xs, wswz,
                                               b_ih, b_hh, L.Xo,
                                               (t == 7) ? fout : nullptr,
                                               P, 7 - t, flags);
        }
    };

    // level 5: leaves as children (h0 = 0)
    run_level(XA, nullptr, L5, nullptr, 4096, true);
    run_level(L5.Xo, L5.Hf, L4, nullptr, 512, false);
    run_level(L4.Xo, L4.Hf, L3, nullptr, 64, false);
    run_level(L3.Xo, L3.Hf, L2, nullptr, 8, false);
    run_level(L2.Xo, L2.Hf, L1, out, 1, false);
}

// Round 4
// 954.685 us; speedup vs baseline: 1.4477x; 1.3926x over previous
//
#include <hip/hip_runtime.h>
#include <hip/hip_bf16.h>
#include <stdint.h>

typedef float f32x4 __attribute__((ext_vector_type(4)));
typedef short bf16x8 __attribute__((ext_vector_type(8)));

__device__ __forceinline__ ushort to_bf16(float f) {
    union { float f; uint32_t u; } v; v.f = f;
    uint32_t u = v.u;
    return (ushort)((u + 0x7fffu + ((u >> 16) & 1u)) >> 16);   // RNE
}
__device__ __forceinline__ float sigmoid_(float x) { return 1.0f / (1.0f + __expf(-x)); }
__device__ __forceinline__ float tanh_(float x)    { return 1.0f - 2.0f / (__expf(2.0f * x) + 1.0f); }

// Swizzled concat weight W'[g][k] = (k<384 ? w_ih : w_hh), bf16; fragment layout:
// elem ((tile*24 + kc)*64 + quad*16 + (g&15))*8 + j  for k = kc*32 + quad*8 + j
__global__ void prep_w(const float* __restrict__ w_ih, const float* __restrict__ w_hh,
                       ushort* __restrict__ wswz) {
    int tid = blockIdx.x * blockDim.x + threadIdx.x;   // 1152 * 96
    if (tid >= 1152 * 96) return;
    int g  = tid / 96;
    int k  = (tid % 96) * 8;
    int kc = k >> 5;
    int q  = (k >> 3) & 3;
    int tile = g >> 4;
    int lane = q * 16 + (g & 15);
    ushort* dst = wswz + ((size_t)(tile * 24 + kc) * 64 + lane) * 8;
    const float* src = (k < 384) ? (w_ih + (size_t)g * 384 + k)
                                 : (w_hh + (size_t)g * 384 + (k - 384));
#pragma unroll
    for (int j = 0; j < 8; ++j) dst[j] = to_bf16(src[j]);
}

__global__ void embed_gather(const int* __restrict__ tok, const float* __restrict__ table,
                             ushort* __restrict__ xleaf, int n_leaves) {
    int tid = blockIdx.x * blockDim.x + threadIdx.x;   // n_leaves * 48
    if (tid >= n_leaves * 48) return;
    int leaf = tid / 48, i = tid % 48;
    const float* src = table + (size_t)tok[leaf] * 384 + i * 8;
    bf16x8 v;
#pragma unroll
    for (int j = 0; j < 8; ++j) v[j] = (short)to_bf16(src[j]);
    *(bf16x8*)(xleaf + (size_t)leaf * 384 + i * 8) = v;
}

// Tail-level init: h0 = mean of 8 children's f32 hidden states. Writes the t=-1
// ping-pong buffer (Hb) + the f32 master Hf.
__global__ void init_h(const float* __restrict__ Hc, float* __restrict__ Hf,
                       ushort* __restrict__ Hb, int P) {
    int tid = blockIdx.x * blockDim.x + threadIdx.x;
    if (tid >= P * 384) return;
    int p = tid / 384, d = tid % 384;
    float h0 = 0.0f;
#pragma unroll
    for (int c = 0; c < 8; ++c) h0 += Hc[((size_t)p * 8 + c) * 384 + d];
    h0 *= 0.125f;
    Hf[tid] = h0; Hb[tid] = to_bf16(h0);
}

// One GRU step. No LDS, no barriers. Block = 256 thr (4 waves); each wave owns
// 32 rows (2 m-tiles) so every B fragment feeds 2 MFMAs; all 4 waves share the
// same 16-dim gate slice ds = blockIdx.y (3 tiles: r, z, n -> 73.7 KB, L1-hot).
// Grid (gx, 24) with gx padded to a multiple of 8: linear id = bx + gx*ds, so
// all 24 ds-blocks of one m-group land on ONE XCD (stride gx ≡ 0 mod 8) and
// x/h stay in that XCD's L2 across steps.
// flags: 1 = first step (xsum write-only), 2 = h is zero (leaf t0), 4 = last step.
__global__ __launch_bounds__(256)
void gru_step(const ushort* __restrict__ Xc, const ushort* __restrict__ Hb_in,
              ushort* __restrict__ Hb_out, float* __restrict__ Hf,
              float* __restrict__ xsum, const ushort* __restrict__ W,
              const float* __restrict__ b_ih, const float* __restrict__ b_hh,
              ushort* __restrict__ Xo, float* __restrict__ fout,
              int P, int child, int flags) {
    const int wave = threadIdx.x >> 6, lane = threadIdx.x & 63;
    const int quad = lane >> 4, col = lane & 15;
    const int m0 = (blockIdx.x * 4 + wave) * 32;    // wave's rows [m0, m0+32)
    if (m0 >= P) return;                            // padded/overshoot blocks exit
    const int ds = blockIdx.y;                      // dims [ds*16, ds*16+16)
    const bool first = (flags & 1) != 0, hzero = (flags & 2) != 0, last = (flags & 4) != 0;
    const bool do2 = (m0 + 16) < P;                 // wave-uniform

    const int par0 = m0 + col, par1 = m0 + 16 + col;
    const bool av0 = par0 < P, av1 = par1 < P;
    const ushort* xr0 = Xc + ((size_t)par0 * 8 + child) * 384 + quad * 8;
    const ushort* xr1 = Xc + ((size_t)par1 * 8 + child) * 384 + quad * 8;
    const ushort* hr0 = Hb_in + (size_t)par0 * 384 + quad * 8;
    const ushort* hr1 = Hb_in + (size_t)par1 * 384 + quad * 8;
    const ushort* Wl = W + (size_t)lane * 8;
    const size_t oR = (size_t)ds * 12288;
    const size_t oZ = (size_t)(24 + ds) * 12288;
    const size_t oN = (size_t)(48 + ds) * 12288;

    f32x4 z4 = (f32x4){0.f, 0.f, 0.f, 0.f};
    f32x4 accr0 = z4, accz0 = z4, accn10 = z4, accn20 = z4;
    f32x4 accr1 = z4, accz1 = z4, accn11 = z4, accn21 = z4;
    const bf16x8 zf = (bf16x8){0, 0, 0, 0, 0, 0, 0, 0};

    const int kcmax = hzero ? 12 : 24;              // h==0: skip the h half
    for (int kc = 0; kc < kcmax; ++kc) {
        bf16x8 a0 = zf, a1 = zf;
        if (av0) a0 = *(const bf16x8*)((kc < 12) ? (xr0 + kc * 32) : (hr0 + (kc - 12) * 32));
        if (do2 && av1) a1 = *(const bf16x8*)((kc < 12) ? (xr1 + kc * 32) : (hr1 + (kc - 12) * 32));
        const size_t kb = (size_t)kc * 512;
        bf16x8 bR = *(const bf16x8*)(Wl + oR + kb);
        accr0 = __builtin_amdgcn_mfma_f32_16x16x32_bf16(a0, bR, accr0, 0, 0, 0);
        if (do2) accr1 = __builtin_amdgcn_mfma_f32_16x16x32_bf16(a1, bR, accr1, 0, 0, 0);
        bf16x8 bZ = *(const bf16x8*)(Wl + oZ + kb);
        accz0 = __builtin_amdgcn_mfma_f32_16x16x32_bf16(a0, bZ, accz0, 0, 0, 0);
        if (do2) accz1 = __builtin_amdgcn_mfma_f32_16x16x32_bf16(a1, bZ, accz1, 0, 0, 0);
        bf16x8 bN = *(const bf16x8*)(Wl + oN + kb);
        if (kc < 12) {
            accn10 = __builtin_amdgcn_mfma_f32_16x16x32_bf16(a0, bN, accn10, 0, 0, 0);
            if (do2) accn11 = __builtin_amdgcn_mfma_f32_16x16x32_bf16(a1, bN, accn11, 0, 0, 0);
        } else {
            accn20 = __builtin_amdgcn_mfma_f32_16x16x32_bf16(a0, bN, accn20, 0, 0, 0);
            if (do2) accn21 = __builtin_amdgcn_mfma_f32_16x16x32_bf16(a1, bN, accn21, 0, 0, 0);
        }
    }

    const int d = ds * 16 + col;
    const float br = b_ih[d] + b_hh[d];
    const float bz = b_ih[384 + d] + b_hh[384 + d];
    const float bi = b_ih[768 + d], bh = b_hh[768 + d];
#pragma unroll
    for (int mt = 0; mt < 2; ++mt) {
        if (mt && !do2) break;
        const f32x4 ar  = mt ? accr1  : accr0;
        const f32x4 az  = mt ? accz1  : accz0;
        const f32x4 an1 = mt ? accn11 : accn10;
        const f32x4 an2 = mt ? accn21 : accn20;
#pragma unroll
        for (int r = 0; r < 4; ++r) {
            const int m = m0 + mt * 16 + quad * 4 + r;
            if (m < P) {
                const size_t idx = (size_t)m * 384 + d;
                float rv = sigmoid_(ar[r] + br);
                float zv = sigmoid_(az[r] + bz);
                float nv = tanh_(an1[r] + bi + rv * (an2[r] + bh));
                float hp = hzero ? 0.0f : Hf[idx];
                float hn = (1.0f - zv) * nv + zv * hp;
                Hf[idx] = hn;
                Hb_out[idx] = to_bf16(hn);
                float xs = first ? hn : xsum[idx] + hn;
                if (!last) {
                    xsum[idx] = xs;
                } else {
                    float xo = xs * 0.125f;
                    Xo[idx] = to_bf16(xo);
                    if (fout != nullptr && m == 0) fout[d] = xo;
                }
            }
        }
    }
}

extern "C" void kernel_launch(void* const* d_in, const int* in_sizes, int n_in,
                              void* d_out, int out_size, void* d_ws, size_t ws_size,
                              hipStream_t stream) {
    const int*   tok   = (const int*)d_in[0];
    const float* table = (const float*)d_in[1];
    const float* w_ih  = (const float*)d_in[2];
    const float* w_hh  = (const float*)d_in[3];
    const float* b_ih  = (const float*)d_in[4];
    const float* b_hh  = (const float*)d_in[5];
    float* out = (float*)d_out;

    char* ws = (char*)d_ws;
    size_t off = 0;
    auto alloc = [&](size_t bytes) -> void* {
        void* p = ws + off;
        off = (off + bytes + 255) & ~(size_t)255;
        return p;
    };
    ushort* wswz = (ushort*)alloc((size_t)1152 * 768 * 2);
    ushort* XA   = (ushort*)alloc((size_t)32768 * 384 * 2);   // leaf x (bf16)

    struct Lvl { ushort *Ha, *Hb, *Xo; float *Hf, *xs; };
    auto mk = [&](int P) -> Lvl {
        Lvl l;
        l.Ha = (ushort*)alloc((size_t)P * 384 * 2);
        l.Hb = (ushort*)alloc((size_t)P * 384 * 2);
        l.Xo = (ushort*)alloc((size_t)P * 384 * 2);
        l.Hf = (float*) alloc((size_t)P * 384 * 4);
        l.xs = (float*) alloc((size_t)P * 384 * 4);
        return l;
    };
    Lvl L5 = mk(4096), L4 = mk(512), L3 = mk(64), L2 = mk(8), L1 = mk(1);

    prep_w<<<(1152 * 96 + 255) / 256, 256, 0, stream>>>(w_ih, w_hh, wswz);
    embed_gather<<<(32768 * 48 + 255) / 256, 256, 0, stream>>>(tok, table, XA, 32768);

    // Ping-pong parity: init writes Hb ("t=-1 output"); step t reads (t&1)?Ha:Hb
    // and writes (t&1)?Hb:Ha -> every step reads the previous step's buffer.
    auto run_level = [&](const ushort* Xc, const float* Hc_child, Lvl& L,
                         float* fout, int P, bool leaf) {
        if (!leaf)
            init_h<<<(P * 384 + 255) / 256, 256, 0, stream>>>(Hc_child, L.Hf, L.Hb, P);
        int gx = (P + 127) / 128;
        gx = (gx + 7) & ~7;                     // pad for XCD colocation
        dim3 grid(gx, 24);
        for (int t = 0; t < 8; ++t) {
            const ushort* hin = (t & 1) ? L.Ha : L.Hb;
            ushort*       hout = (t & 1) ? L.Hb : L.Ha;
            int flags = (t == 0 ? 1 : 0) | ((leaf && t == 0) ? 2 : 0) | (t == 7 ? 4 : 0);
            gru_step<<<grid, 256, 0, stream>>>(Xc, hin, hout, L.Hf, L.xs, wswz,
                                               b_ih, b_hh, L.Xo,
                                               (t == 7) ? fout : nullptr,
                                               P, 7 - t, flags);
        }
    };

    run_level(XA, nullptr, L5, nullptr, 4096, true);
    run_level(L5.Xo, L5.Hf, L4, nullptr, 512, false);
    run_level(L4.Xo, L4.Hf, L3, nullptr, 64, false);
    run_level(L3.Xo, L3.Hf, L2, nullptr, 8, false);
    run_level(L2.Xo, L2.Hf, L1, out, 1, false);
}

// Round 5
// 659.095 us; speedup vs baseline: 2.0969x; 1.4485x over previous
//
#include <hip/hip_runtime.h>
#include <hip/hip_bf16.h>
#include <stdint.h>

typedef float f32x4 __attribute__((ext_vector_type(4)));
typedef short bf16x8 __attribute__((ext_vector_type(8)));

__device__ __forceinline__ ushort to_bf16(float f) {
    union { float f; uint32_t u; } v; v.f = f;
    uint32_t u = v.u;
    return (ushort)((u + 0x7fffu + ((u >> 16) & 1u)) >> 16);   // RNE
}
__device__ __forceinline__ float sigmoid_(float x) { return 1.0f / (1.0f + __expf(-x)); }
__device__ __forceinline__ float tanh_(float x)    { return 1.0f - 2.0f / (__expf(2.0f * x) + 1.0f); }

// Swizzled concat weight W'[g][k] = (k<384 ? w_ih : w_hh), bf16; fragment layout:
// elem ((tile*24 + kc)*64 + quad*16 + (g&15))*8 + j  for k = kc*32 + quad*8 + j
__global__ void prep_w(const float* __restrict__ w_ih, const float* __restrict__ w_hh,
                       ushort* __restrict__ wswz) {
    int tid = blockIdx.x * blockDim.x + threadIdx.x;   // 1152 * 96
    if (tid >= 1152 * 96) return;
    int g  = tid / 96;
    int k  = (tid % 96) * 8;
    int kc = k >> 5;
    int q  = (k >> 3) & 3;
    int tile = g >> 4;
    int lane = q * 16 + (g & 15);
    ushort* dst = wswz + ((size_t)(tile * 24 + kc) * 64 + lane) * 8;
    const float* src = (k < 384) ? (w_ih + (size_t)g * 384 + k)
                                 : (w_hh + (size_t)g * 384 + (k - 384));
#pragma unroll
    for (int j = 0; j < 8; ++j) dst[j] = to_bf16(src[j]);
}

__global__ void embed_gather(const int* __restrict__ tok, const float* __restrict__ table,
                             ushort* __restrict__ xleaf, int n_leaves) {
    int tid = blockIdx.x * blockDim.x + threadIdx.x;   // n_leaves * 48
    if (tid >= n_leaves * 48) return;
    int leaf = tid / 48, i = tid % 48;
    const float* src = table + (size_t)tok[leaf] * 384 + i * 8;
    bf16x8 v;
#pragma unroll
    for (int j = 0; j < 8; ++j) v[j] = (short)to_bf16(src[j]);
    *(bf16x8*)(xleaf + (size_t)leaf * 384 + i * 8) = v;
}

// Tail-level init: h0 = mean of 8 children's final f32 h. Writes HT slot 0 + HB slot 0.
__global__ void init_h(const float* __restrict__ Hc, float* __restrict__ HT0,
                       ushort* __restrict__ HB0, int P) {
    int tid = blockIdx.x * blockDim.x + threadIdx.x;
    if (tid >= P * 384) return;
    int p = tid / 384, d = tid % 384;
    float h0 = 0.0f;
#pragma unroll
    for (int c = 0; c < 8; ++c) h0 += Hc[((size_t)p * 8 + c) * 384 + d];
    h0 *= 0.125f;
    HT0[tid] = h0; HB0[tid] = to_bf16(h0);
}

// One GRU step. No LDS, no barriers. Block = 256 thr (4 waves); each wave owns
// 32 rows (2 m-tiles); all 4 waves share gate slice ds = blockIdx.y (r,z,n tiles
// for dims ds*16..+15 -> full GRU update is lane-local). Grid (gx, 24); for L5
// gx=32 ≡ 0 mod 8 so all 24 ds-blocks of an m-group land on one XCD.
// State: HT = 9 f32 slots (slot t = h after step t-1... slot0 = h0); HB = bf16
// mirror for MFMA A-fragments. Step t reads slot t, writes slot t+1.
// flags: 1 = h_prev is zero (leaf t0), 2 = last step (emit mean -> Xo).
__global__ __launch_bounds__(256, 4)
void gru_step(const ushort* __restrict__ Xc, ushort* __restrict__ HB,
              float* __restrict__ HT, const ushort* __restrict__ W,
              const float* __restrict__ b_ih, const float* __restrict__ b_hh,
              ushort* __restrict__ Xo, float* __restrict__ fout,
              int P, int t, int flags) {
    const int wave = threadIdx.x >> 6, lane = threadIdx.x & 63;
    const int quad = lane >> 4, col = lane & 15;
    const int m0 = (blockIdx.x * 4 + wave) * 32;
    if (m0 >= P) return;
    const int ds = blockIdx.y;
    const bool hzero = (flags & 1) != 0, last = (flags & 2) != 0;
    const bool do2 = (m0 + 16) < P;                  // wave-uniform
    const int child = 7 - t;
    const size_t N = (size_t)P * 384;

    const ushort* HBprev = HB + (size_t)t * N;
    ushort*       HBcur  = HB + (size_t)(t + 1) * N;
    const float*  HTprev = HT + (size_t)t * N;
    float*        HTcur  = HT + (size_t)(t + 1) * N;

    const int par0 = m0 + col, par1 = m0 + 16 + col;
    const bool av0 = par0 < P, av1 = par1 < P;
    const ushort* xr0 = Xc + ((size_t)par0 * 8 + child) * 384 + quad * 8;
    const ushort* xr1 = Xc + ((size_t)par1 * 8 + child) * 384 + quad * 8;
    const ushort* hr0 = HBprev + (size_t)par0 * 384 + quad * 8;
    const ushort* hr1 = HBprev + (size_t)par1 * 384 + quad * 8;
    const ushort* Wl = W + (size_t)lane * 8;
    const size_t oR = (size_t)ds * 12288;
    const size_t oZ = (size_t)(24 + ds) * 12288;
    const size_t oN = (size_t)(48 + ds) * 12288;

    // Pre-issue lane-local state: biases + previous h (f32) for the update.
    const int d = ds * 16 + col;
    const float br = b_ih[d] + b_hh[d];
    const float bz = b_ih[384 + d] + b_hh[384 + d];
    const float bi = b_ih[768 + d], bh = b_hh[768 + d];
    float hp[2][4];
#pragma unroll
    for (int mt = 0; mt < 2; ++mt)
#pragma unroll
        for (int r = 0; r < 4; ++r) {
            int m = m0 + mt * 16 + quad * 4 + r;
            hp[mt][r] = (!hzero && m < P) ? HTprev[(size_t)m * 384 + d] : 0.0f;
        }

    f32x4 z4 = (f32x4){0.f, 0.f, 0.f, 0.f};
    f32x4 accr0 = z4, accz0 = z4, accn10 = z4, accn20 = z4;
    f32x4 accr1 = z4, accz1 = z4, accn11 = z4, accn21 = z4;
    const bf16x8 zf = (bf16x8){0, 0, 0, 0, 0, 0, 0, 0};

    // x half: kc 0..11 (W_ih columns)
#pragma unroll
    for (int kc = 0; kc < 12; ++kc) {
        bf16x8 a0 = zf, a1 = zf;
        if (av0) a0 = *(const bf16x8*)(xr0 + kc * 32);
        if (do2 && av1) a1 = *(const bf16x8*)(xr1 + kc * 32);
        const size_t kb = (size_t)kc * 512;
        bf16x8 bR = *(const bf16x8*)(Wl + oR + kb);
        bf16x8 bZ = *(const bf16x8*)(Wl + oZ + kb);
        bf16x8 bN = *(const bf16x8*)(Wl + oN + kb);
        accr0 = __builtin_amdgcn_mfma_f32_16x16x32_bf16(a0, bR, accr0, 0, 0, 0);
        accz0 = __builtin_amdgcn_mfma_f32_16x16x32_bf16(a0, bZ, accz0, 0, 0, 0);
        accn10 = __builtin_amdgcn_mfma_f32_16x16x32_bf16(a0, bN, accn10, 0, 0, 0);
        if (do2) {
            accr1 = __builtin_amdgcn_mfma_f32_16x16x32_bf16(a1, bR, accr1, 0, 0, 0);
            accz1 = __builtin_amdgcn_mfma_f32_16x16x32_bf16(a1, bZ, accz1, 0, 0, 0);
            accn11 = __builtin_amdgcn_mfma_f32_16x16x32_bf16(a1, bN, accn11, 0, 0, 0);
        }
    }
    // h half: kc 12..23 (W_hh columns) — skipped when h == 0
    if (!hzero) {
#pragma unroll
        for (int kc = 0; kc < 12; ++kc) {
            bf16x8 a0 = zf, a1 = zf;
            if (av0) a0 = *(const bf16x8*)(hr0 + kc * 32);
            if (do2 && av1) a1 = *(const bf16x8*)(hr1 + kc * 32);
            const size_t kb = (size_t)(12 + kc) * 512;
            bf16x8 bR = *(const bf16x8*)(Wl + oR + kb);
            bf16x8 bZ = *(const bf16x8*)(Wl + oZ + kb);
            bf16x8 bN = *(const bf16x8*)(Wl + oN + kb);
            accr0 = __builtin_amdgcn_mfma_f32_16x16x32_bf16(a0, bR, accr0, 0, 0, 0);
            accz0 = __builtin_amdgcn_mfma_f32_16x16x32_bf16(a0, bZ, accz0, 0, 0, 0);
            accn20 = __builtin_amdgcn_mfma_f32_16x16x32_bf16(a0, bN, accn20, 0, 0, 0);
            if (do2) {
                accr1 = __builtin_amdgcn_mfma_f32_16x16x32_bf16(a1, bR, accr1, 0, 0, 0);
                accz1 = __builtin_amdgcn_mfma_f32_16x16x32_bf16(a1, bZ, accz1, 0, 0, 0);
                accn21 = __builtin_amdgcn_mfma_f32_16x16x32_bf16(a1, bN, accn21, 0, 0, 0);
            }
        }
    }

#pragma unroll
    for (int mt = 0; mt < 2; ++mt) {
        if (mt && !do2) break;
        const f32x4 ar  = mt ? accr1  : accr0;
        const f32x4 az  = mt ? accz1  : accz0;
        const f32x4 an1 = mt ? accn11 : accn10;
        const f32x4 an2 = mt ? accn21 : accn20;
#pragma unroll
        for (int r = 0; r < 4; ++r) {
            const int m = m0 + mt * 16 + quad * 4 + r;
            if (m < P) {
                const size_t idx = (size_t)m * 384 + d;
                float rv = sigmoid_(ar[r] + br);
                float zv = sigmoid_(az[r] + bz);
                float nv = tanh_(an1[r] + bi + rv * (an2[r] + bh));
                float hn = (1.0f - zv) * nv + zv * hp[mt][r];
                HTcur[idx] = hn;
                HBcur[idx] = to_bf16(hn);
                if (last) {
                    // outs mean: h_1..h_8 = HT slots 1..7 + hn (slot7 == hp, already loaded)
                    float xs = hn + hp[mt][r];
#pragma unroll
                    for (int s = 1; s <= 6; ++s) xs += HT[(size_t)s * N + idx];
                    float xo = xs * 0.125f;
                    Xo[idx] = to_bf16(xo);
                    if (fout != nullptr && m == 0) fout[d] = xo;
                }
            }
        }
    }
}

extern "C" void kernel_launch(void* const* d_in, const int* in_sizes, int n_in,
                              void* d_out, int out_size, void* d_ws, size_t ws_size,
                              hipStream_t stream) {
    const int*   tok   = (const int*)d_in[0];
    const float* table = (const float*)d_in[1];
    const float* w_ih  = (const float*)d_in[2];
    const float* w_hh  = (const float*)d_in[3];
    const float* b_ih  = (const float*)d_in[4];
    const float* b_hh  = (const float*)d_in[5];
    float* out = (float*)d_out;

    char* ws = (char*)d_ws;
    size_t off = 0;
    auto alloc = [&](size_t bytes) -> void* {
        void* p = ws + off;
        off = (off + bytes + 255) & ~(size_t)255;
        return p;
    };
    ushort* wswz = (ushort*)alloc((size_t)1152 * 768 * 2);
    ushort* XA   = (ushort*)alloc((size_t)32768 * 384 * 2);   // leaf x (bf16)

    struct Lvl { ushort *HB, *Xo; float *HT; int P; };
    auto mk = [&](int P) -> Lvl {
        Lvl l; l.P = P;
        size_t N = (size_t)P * 384;
        l.HB = (ushort*)alloc(9 * N * 2);   // bf16 h slots 0..8
        l.HT = (float*) alloc(9 * N * 4);   // f32  h slots 0..8
        l.Xo = (ushort*)alloc(N * 2);
        return l;
    };
    Lvl L5 = mk(4096), L4 = mk(512), L3 = mk(64), L2 = mk(8), L1 = mk(1);

    prep_w<<<(1152 * 96 + 255) / 256, 256, 0, stream>>>(w_ih, w_hh, wswz);
    embed_gather<<<(32768 * 48 + 255) / 256, 256, 0, stream>>>(tok, table, XA, 32768);

    auto run_level = [&](const ushort* Xc, const float* Hc_child, Lvl& L,
                         float* fout, bool leaf) {
        int P = L.P;
        if (!leaf)
            init_h<<<(P * 384 + 255) / 256, 256, 0, stream>>>(Hc_child, L.HT, L.HB, P);
        int gx = (P + 127) / 128;
        dim3 grid(gx, 24);
        for (int t = 0; t < 8; ++t) {
            int flags = ((leaf && t == 0) ? 1 : 0) | (t == 7 ? 2 : 0);
            gru_step<<<grid, 256, 0, stream>>>(Xc, L.HB, L.HT, wswz, b_ih, b_hh,
                                               L.Xo, (t == 7) ? fout : nullptr,
                                               P, t, flags);
        }
    };

    run_level(XA, nullptr, L5, nullptr, true);
    run_level(L5.Xo, L5.HT + (size_t)8 * 4096 * 384, L4, nullptr, false);
    run_level(L4.Xo, L4.HT + (size_t)8 * 512 * 384,  L3, nullptr, false);
    run_level(L3.Xo, L3.HT + (size_t)8 * 64 * 384,   L2, nullptr, false);
    run_level(L2.Xo, L2.HT + (size_t)8 * 8 * 384,    L1, out,     false);
}